// Round 3
// baseline (308.819 us; speedup 1.0000x reference)
//
#include <hip/hip_runtime.h>
#include <math.h>

#define NT 262144
#define KD 512
#define NE 64
#define DE 64

constexpr int BM = 128;   // tokens per block
constexpr int LA = 132;   // LDS stride for h_norm [d][tok]
constexpr int WS_EN = 49152;  // u32 offset of e_norm^T region in workspace

using f32x4 = __attribute__((ext_vector_type(4))) float;
using s16x8 = __attribute__((ext_vector_type(8))) short;

// ---- 3-term truncated bf16 split of fp32: x = x1 + x2 + x3, |res| <= 2^-24|x| ----
// Packs two consecutive elements per u32 (low short = even elem).
__device__ __forceinline__ void split8(float4 lo, float4 hi,
                                       s16x8& o1, s16x8& o2, s16x8& o3) {
    float x[8] = {lo.x, lo.y, lo.z, lo.w, hi.x, hi.y, hi.z, hi.w};
    union { unsigned int u[4]; s16x8 v; } r1, r2, r3;
    #pragma unroll
    for (int p = 0; p < 4; ++p) {
        float f0 = x[2 * p], f1 = x[2 * p + 1];
        unsigned int a = __float_as_uint(f0), b = __float_as_uint(f1);
        unsigned int a1 = a & 0xFFFF0000u, b1 = b & 0xFFFF0000u;
        r1.u[p] = (a1 >> 16) | b1;
        float q0 = f0 - __uint_as_float(a1);
        float q1 = f1 - __uint_as_float(b1);
        unsigned int a2 = __float_as_uint(q0) & 0xFFFF0000u;
        unsigned int b2 = __float_as_uint(q1) & 0xFFFF0000u;
        r2.u[p] = (a2 >> 16) | b2;
        float s0 = q0 - __uint_as_float(a2);
        float s1 = q1 - __uint_as_float(b2);
        r3.u[p] = (__float_as_uint(s0) >> 16) | (__float_as_uint(s1) & 0xFFFF0000u);
    }
    o1 = r1.v; o2 = r2.v; o3 = r3.v;
}

__device__ __forceinline__ s16x8 ld_frag(const unsigned int* p) {
    union { uint4 q; s16x8 v; } u;
    u.q = *(const uint4*)p;
    return u.v;
}

// ---- prep: blocks 0..15 split W into plane-interleaved bf16 fragments;
//      block 16 writes e_norm^T fp32. ws layout:
//      [0, 49152) u32 : W frags, chunk c=(row*64+k8) at c*12: {p1[4], p2[4], p3[4]}
//      [49152, +4096) as float: e_norm^T [d][expert]
__global__ void prep(const float* __restrict__ W, const float* __restrict__ E,
                     unsigned int* __restrict__ ws) {
    const int tid = threadIdx.x;
    if (blockIdx.x < 16) {
        const int idx = blockIdx.x * 256 + tid;     // chunk: row*64 + k8
        const int row = idx >> 6, k8 = idx & 63;
        const float* src = W + (size_t)row * KD + k8 * 8;
        float4 lo = *(const float4*)src, hi = *(const float4*)(src + 4);
        s16x8 o1, o2, o3;
        split8(lo, hi, o1, o2, o3);
        union { s16x8 v; uint4 q; } u1, u2, u3;
        u1.v = o1; u2.v = o2; u3.v = o3;
        uint4* dst = (uint4*)(ws + (size_t)idx * 12);
        dst[0] = u1.q; dst[1] = u2.q; dst[2] = u3.q;
    } else {
        float* en = (float*)(ws + WS_EN);
        const int er = tid >> 2, part = tid & 3;
        float ss = 0.f;
        float4 ev[4];
        #pragma unroll
        for (int u = 0; u < 4; ++u) {
            ev[u] = *(const float4*)(E + er * DE + part * 16 + u * 4);
            ss = fmaf(ev[u].x, ev[u].x, ss);
            ss = fmaf(ev[u].y, ev[u].y, ss);
            ss = fmaf(ev[u].z, ev[u].z, ss);
            ss = fmaf(ev[u].w, ev[u].w, ss);
        }
        ss += __shfl_xor(ss, 1, 64);
        ss += __shfl_xor(ss, 2, 64);
        const float inv_e = 1.0f / fmaxf(sqrtf(ss), 1e-12f);
        #pragma unroll
        for (int u = 0; u < 4; ++u) {
            int d = part * 16 + u * 4;
            en[(d + 0) * 64 + er] = ev[u].x * inv_e;
            en[(d + 1) * 64 + er] = ev[u].y * inv_e;
            en[(d + 2) * 64 + er] = ev[u].z * inv_e;
            en[(d + 3) * 64 + er] = ev[u].w * inv_e;
        }
    }
}

// One stage-1 K-step: consume A buffer (split to bf16), reload it 2 steps
// ahead, run 4 ct x 12 MFMA. All indices static (no scratch).
#define S1_STEP(AL0, AH0, AL1, AH1, KS)                                        \
    {                                                                          \
        s16x8 a1[2], a2[2], a3[2];                                             \
        split8(AL0, AH0, a1[0], a2[0], a3[0]);                                 \
        split8(AL1, AH1, a1[1], a2[1], a3[1]);                                 \
        if ((KS) + 2 < KD / 32) {                                              \
            const int o = ((KS) + 2) * 32;                                     \
            AL0 = *(const float4*)(pa0 + o); AH0 = *(const float4*)(pa0 + o + 4); \
            AL1 = *(const float4*)(pa1 + o); AH1 = *(const float4*)(pa1 + o + 4); \
        }                                                                      \
        const int k8 = (KS) * 4 + lk;                                          \
        _Pragma("unroll")                                                      \
        for (int ct = 0; ct < 4; ++ct) {                                       \
            const int bi = ((ct * 16 + lr) * 64 + k8) * 12;                    \
            s16x8 b1 = ld_frag(wsW + bi);                                      \
            s16x8 b2 = ld_frag(wsW + bi + 4);                                  \
            s16x8 b3 = ld_frag(wsW + bi + 8);                                  \
            f32x4 c0 = acc[0][ct], c1 = acc[1][ct];                            \
            c0 = __builtin_amdgcn_mfma_f32_16x16x32_bf16(a1[0], b1, c0, 0, 0, 0); \
            c1 = __builtin_amdgcn_mfma_f32_16x16x32_bf16(a1[1], b1, c1, 0, 0, 0); \
            c0 = __builtin_amdgcn_mfma_f32_16x16x32_bf16(a2[0], b1, c0, 0, 0, 0); \
            c1 = __builtin_amdgcn_mfma_f32_16x16x32_bf16(a2[1], b1, c1, 0, 0, 0); \
            c0 = __builtin_amdgcn_mfma_f32_16x16x32_bf16(a1[0], b2, c0, 0, 0, 0); \
            c1 = __builtin_amdgcn_mfma_f32_16x16x32_bf16(a1[1], b2, c1, 0, 0, 0); \
            c0 = __builtin_amdgcn_mfma_f32_16x16x32_bf16(a3[0], b1, c0, 0, 0, 0); \
            c1 = __builtin_amdgcn_mfma_f32_16x16x32_bf16(a3[1], b1, c1, 0, 0, 0); \
            c0 = __builtin_amdgcn_mfma_f32_16x16x32_bf16(a2[0], b2, c0, 0, 0, 0); \
            c1 = __builtin_amdgcn_mfma_f32_16x16x32_bf16(a2[1], b2, c1, 0, 0, 0); \
            c0 = __builtin_amdgcn_mfma_f32_16x16x32_bf16(a1[0], b3, c0, 0, 0, 0); \
            c1 = __builtin_amdgcn_mfma_f32_16x16x32_bf16(a1[1], b3, c1, 0, 0, 0); \
            acc[0][ct] = c0; acc[1][ct] = c1;                                  \
        }                                                                      \
    }

// ---- fused main: MFMA split-bf16 proj -> norm -> scores -> softmax -> top2 ----
// Stage-1: no LDS, no barriers; A from global h (coalesced), 2-deep prefetch;
// B from plane-interleaved W-splits (L1-hot, 48B/fragment-triple).
// LDS only holds h_norm (33KB) -> 4 blocks/CU.
__global__ __launch_bounds__(256, 4) void moe_all(const float* __restrict__ h,
                                                  const unsigned int* __restrict__ wsW,
                                                  const float* __restrict__ enorm,
                                                  const float* __restrict__ tau_p,
                                                  float* __restrict__ out) {
    __shared__ float s_hn[DE * LA];   // stage2: h_norm [d][tok]

    const int tid = threadIdx.x;
    const int lane = tid & 63;
    const int wv = tid >> 6;          // wave 0..3 -> tokens [wv*32, wv*32+32)
    const int lr = lane & 15;         // fragment row/col within 16
    const int lk = lane >> 4;         // k-group 0..3
    const long tok0 = (long)blockIdx.x * BM;
    const long wtok = tok0 + wv * 32;

    f32x4 acc[2][4];                  // [row-tile][col-tile], 16x16 each
    #pragma unroll
    for (int rt = 0; rt < 2; ++rt)
        #pragma unroll
        for (int ct = 0; ct < 4; ++ct)
            acc[rt][ct] = (f32x4){0.f, 0.f, 0.f, 0.f};

    const float* pa0 = h + (wtok + 0 * 16 + lr) * (long)KD + lk * 8;
    const float* pa1 = h + (wtok + 1 * 16 + lr) * (long)KD + lk * 8;

    // two A buffers, 2-deep prefetch
    float4 xlo0 = *(const float4*)(pa0),      xhi0 = *(const float4*)(pa0 + 4);
    float4 xlo1 = *(const float4*)(pa1),      xhi1 = *(const float4*)(pa1 + 4);
    float4 ylo0 = *(const float4*)(pa0 + 32), yhi0 = *(const float4*)(pa0 + 36);
    float4 ylo1 = *(const float4*)(pa1 + 32), yhi1 = *(const float4*)(pa1 + 36);

    for (int ks = 0; ks < KD / 32; ks += 2) {
        S1_STEP(xlo0, xhi0, xlo1, xhi1, ks);
        S1_STEP(ylo0, yhi0, ylo1, yhi1, ks + 1);
    }

    // ---- per-token L2 norm from fragments ----
    // C/D layout: col = lane&15 (d), row = (lane>>4)*4 + reg (token within 16)
    float inv_n[2][4];
    #pragma unroll
    for (int rt = 0; rt < 2; ++rt) {
        #pragma unroll
        for (int r = 0; r < 4; ++r) {
            float ss = 0.f;
            #pragma unroll
            for (int ct = 0; ct < 4; ++ct)
                ss = fmaf(acc[rt][ct][r], acc[rt][ct][r], ss);
            ss += __shfl_xor(ss, 1, 64);
            ss += __shfl_xor(ss, 2, 64);
            ss += __shfl_xor(ss, 4, 64);
            ss += __shfl_xor(ss, 8, 64);
            inv_n[rt][r] = 1.0f / fmaxf(sqrtf(ss), 1e-12f);
        }
    }

    // h_norm -> LDS [d][tok] (one-time scatter, 2-way banks with LA=132)
    #pragma unroll
    for (int rt = 0; rt < 2; ++rt)
        #pragma unroll
        for (int ct = 0; ct < 4; ++ct)
            #pragma unroll
            for (int r = 0; r < 4; ++r) {
                const int d = ct * 16 + lr;
                const int t = wv * 32 + rt * 16 + lk * 4 + r;
                s_hn[d * LA + t] = acc[rt][ct][r] * inv_n[rt][r];
            }
    __syncthreads();   // the only block barrier

    // ---- stage 2: scores[128][64] = h_norm @ e_norm^T (K=64), fp32 VALU ----
    // B read straight from global e_norm^T (16KB, L1-resident).
    const int tx = tid & 15;   // cols tx*4 + j
    const int ty = tid >> 4;   // tokens p*64 + ty*4 + i
    float sacc[2][4][4];
    #pragma unroll
    for (int p = 0; p < 2; ++p)
        #pragma unroll
        for (int i = 0; i < 4; ++i)
            #pragma unroll
            for (int j = 0; j < 4; ++j) sacc[p][i][j] = 0.0f;

    #pragma unroll 8
    for (int dd = 0; dd < DE; ++dd) {
        const float* ra = s_hn + dd * LA;
        float4 a0 = *(const float4*)(ra + ty * 4);
        float4 a1v = *(const float4*)(ra + 64 + ty * 4);
        float4 b  = *(const float4*)(enorm + dd * 64 + tx * 4);
        float av[2][4] = {{a0.x, a0.y, a0.z, a0.w}, {a1v.x, a1v.y, a1v.z, a1v.w}};
        float bv[4] = {b.x, b.y, b.z, b.w};
        #pragma unroll
        for (int p = 0; p < 2; ++p)
            #pragma unroll
            for (int i = 0; i < 4; ++i)
                #pragma unroll
                for (int j = 0; j < 4; ++j)
                    sacc[p][i][j] = fmaf(av[p][i], bv[j], sacc[p][i][j]);
    }

    // ---- epilogue: softmax, top-2, outputs ----
    const float inv_tau = 1.0f / tau_p[0];
    float* outS = out;                        // sparse_gates [NT][64]
    float* outI = out + (size_t)NT * 64;      // topk_indices [NT][2] (as float)
    float* outF = out + (size_t)NT * 66;      // full_gates   [NT][64]

    #pragma unroll
    for (int p = 0; p < 2; ++p) {
        #pragma unroll
        for (int i = 0; i < 4; ++i) {
            const long tok = tok0 + p * 64 + ty * 4 + i;
            float s[4];
            #pragma unroll
            for (int j = 0; j < 4; ++j) s[j] = sacc[p][i][j] * inv_tau;

            float m = fmaxf(fmaxf(s[0], s[1]), fmaxf(s[2], s[3]));
            m = fmaxf(m, __shfl_xor(m, 1, 64));
            m = fmaxf(m, __shfl_xor(m, 2, 64));
            m = fmaxf(m, __shfl_xor(m, 4, 64));
            m = fmaxf(m, __shfl_xor(m, 8, 64));

            float g[4], z = 0.f;
            #pragma unroll
            for (int j = 0; j < 4; ++j) { g[j] = __expf(s[j] - m); z += g[j]; }
            z += __shfl_xor(z, 1, 64);
            z += __shfl_xor(z, 2, 64);
            z += __shfl_xor(z, 4, 64);
            z += __shfl_xor(z, 8, 64);
            const float invZ = 1.0f / z;

            *(float4*)(outF + tok * 64 + tx * 4) =
                make_float4(g[0] * invZ, g[1] * invZ, g[2] * invZ, g[3] * invZ);

            // top-2 on s (monotone with gates); ties -> lower index (jax top_k)
            float v1 = -3.4e38f, v2 = -3.4e38f;
            int i1 = 1 << 20, i2 = 1 << 20;
            #pragma unroll
            for (int j = 0; j < 4; ++j) {
                float v = s[j];
                int e = tx * 4 + j;
                if (v > v1 || (v == v1 && e < i1)) { v2 = v1; i2 = i1; v1 = v; i1 = e; }
                else if (v > v2 || (v == v2 && e < i2)) { v2 = v; i2 = e; }
            }
            #pragma unroll
            for (int msk = 1; msk <= 8; msk <<= 1) {
                float o1 = __shfl_xor(v1, msk, 64); int oi1 = __shfl_xor(i1, msk, 64);
                float o2 = __shfl_xor(v2, msk, 64); int oi2 = __shfl_xor(i2, msk, 64);
                if (o1 > v1 || (o1 == v1 && oi1 < i1)) {
                    if (v1 > o2 || (v1 == o2 && i1 < oi2)) { v2 = v1; i2 = i1; }
                    else { v2 = o2; i2 = oi2; }
                    v1 = o1; i1 = oi1;
                } else {
                    if (o1 > v2 || (o1 == v2 && oi1 < i2)) { v2 = o1; i2 = oi1; }
                }
            }

            // softmax over the two top GATE values
            float gv1 = __expf(v1 - m) * invZ;
            float gv2 = __expf(v2 - m) * invZ;
            float qq = __expf(gv2 - gv1);
            float w1 = 1.0f / (1.0f + qq);
            float w2 = qq * w1;

            float sp[4];
            #pragma unroll
            for (int j = 0; j < 4; ++j) {
                int e = tx * 4 + j;
                sp[j] = (e == i1) ? w1 : ((e == i2) ? w2 : 0.0f);
            }
            *(float4*)(outS + tok * 64 + tx * 4) = make_float4(sp[0], sp[1], sp[2], sp[3]);
            if (tx == 0) {
                *(float2*)(outI + tok * 2) = make_float2((float)i1, (float)i2);
            }
        }
    }
}

extern "C" void kernel_launch(void* const* d_in, const int* in_sizes, int n_in,
                              void* d_out, int out_size, void* d_ws, size_t ws_size,
                              hipStream_t stream) {
    const float* h   = (const float*)d_in[0];
    const float* W   = (const float*)d_in[1];
    const float* E   = (const float*)d_in[2];
    const float* tau = (const float*)d_in[3];
    float* out = (float*)d_out;
    unsigned int* ws = (unsigned int*)d_ws;   // 192KB W frags + 16KB e_norm^T

    prep<<<17, 256, 0, stream>>>(W, E, ws);
    moe_all<<<NT / BM, 256, 0, stream>>>(h, ws, (const float*)(ws + WS_EN), tau, out);
}

// Round 4
// 275.365 us; speedup vs baseline: 1.1215x; 1.1215x over previous
//
#include <hip/hip_runtime.h>
#include <math.h>

#define NT 262144
#define KD 512
#define NE 64
#define DE 64

constexpr int BM = 128;       // tokens per block
constexpr int LA = 132;       // LDS stride for h_norm [d][tok]
constexpr int NS = KD / 32;   // 16 K-steps
constexpr int WS_EN = 49152;  // u32 offset of e_norm^T region in workspace

using f32x4 = __attribute__((ext_vector_type(4))) float;
using s16x8 = __attribute__((ext_vector_type(8))) short;

typedef const __attribute__((address_space(1))) unsigned int* gp1_t;
typedef __attribute__((address_space(3))) unsigned int* lp3_t;

// ---- 3-term truncated bf16 split of fp32: x = x1 + x2 + x3, |res| <= 2^-24|x| ----
__device__ __forceinline__ void split8(float4 lo, float4 hi,
                                       s16x8& o1, s16x8& o2, s16x8& o3) {
    float x[8] = {lo.x, lo.y, lo.z, lo.w, hi.x, hi.y, hi.z, hi.w};
    union { unsigned int u[4]; s16x8 v; } r1, r2, r3;
    #pragma unroll
    for (int p = 0; p < 4; ++p) {
        float f0 = x[2 * p], f1 = x[2 * p + 1];
        unsigned int a = __float_as_uint(f0), b = __float_as_uint(f1);
        unsigned int a1 = a & 0xFFFF0000u, b1 = b & 0xFFFF0000u;
        r1.u[p] = (a1 >> 16) | b1;
        float q0 = f0 - __uint_as_float(a1);
        float q1 = f1 - __uint_as_float(b1);
        unsigned int a2 = __float_as_uint(q0) & 0xFFFF0000u;
        unsigned int b2 = __float_as_uint(q1) & 0xFFFF0000u;
        r2.u[p] = (a2 >> 16) | b2;
        float s0 = q0 - __uint_as_float(a2);
        float s1 = q1 - __uint_as_float(b2);
        r3.u[p] = (__float_as_uint(s0) >> 16) | (__float_as_uint(s1) & 0xFFFF0000u);
    }
    o1 = r1.v; o2 = r2.v; o3 = r3.v;
}

__device__ __forceinline__ s16x8 ld_frag(const unsigned int* p) {
    union { uint4 q; s16x8 v; } u;
    u.q = *(const uint4*)p;
    return u.v;
}

// ---- prep: blocks 0..15 split W into plane-interleaved bf16 fragments;
//      block 16 writes e_norm^T fp32. ----
__global__ void prep(const float* __restrict__ W, const float* __restrict__ E,
                     unsigned int* __restrict__ ws) {
    const int tid = threadIdx.x;
    if (blockIdx.x < 16) {
        const int idx = blockIdx.x * 256 + tid;     // chunk: row*64 + k8
        const int row = idx >> 6, k8 = idx & 63;
        const float* src = W + (size_t)row * KD + k8 * 8;
        float4 lo = *(const float4*)src, hi = *(const float4*)(src + 4);
        s16x8 o1, o2, o3;
        split8(lo, hi, o1, o2, o3);
        union { s16x8 v; uint4 q; } u1, u2, u3;
        u1.v = o1; u2.v = o2; u3.v = o3;
        uint4* dst = (uint4*)(ws + (size_t)idx * 12);
        dst[0] = u1.q; dst[1] = u2.q; dst[2] = u3.q;
    } else {
        float* en = (float*)(ws + WS_EN);
        const int er = tid >> 2, part = tid & 3;
        float ss = 0.f;
        float4 ev[4];
        #pragma unroll
        for (int u = 0; u < 4; ++u) {
            ev[u] = *(const float4*)(E + er * DE + part * 16 + u * 4);
            ss = fmaf(ev[u].x, ev[u].x, ss);
            ss = fmaf(ev[u].y, ev[u].y, ss);
            ss = fmaf(ev[u].z, ev[u].z, ss);
            ss = fmaf(ev[u].w, ev[u].w, ss);
        }
        ss += __shfl_xor(ss, 1, 64);
        ss += __shfl_xor(ss, 2, 64);
        const float inv_e = 1.0f / fmaxf(sqrtf(ss), 1e-12f);
        #pragma unroll
        for (int u = 0; u < 4; ++u) {
            int d = part * 16 + u * 4;
            en[(d + 0) * 64 + er] = ev[u].x * inv_e;
            en[(d + 1) * 64 + er] = ev[u].y * inv_e;
            en[(d + 2) * 64 + er] = ev[u].z * inv_e;
            en[(d + 3) * 64 + er] = ev[u].w * inv_e;
        }
    }
}

// ---- fused main ----
// Stage-1 A-operand path: global h --(global_load_lds, async, no VGPRs)-->
// double-buffered LDS tile [128 tok][32 k] with XOR-pre-swizzled SOURCE
// (slot (t,q) holds global quad q^(t&7); reader applies same XOR -> 2-way
// banks = free). Counted vmcnt(4) + raw s_barrier keeps next-tile loads in
// flight across the barrier (no __syncthreads auto-drain in the loop).
// B-operand: plane-interleaved bf16 W-splits from workspace (L1/L2-hot).
__global__ __launch_bounds__(256, 4) void moe_all(const float* __restrict__ h,
                                                  const unsigned int* __restrict__ wsW,
                                                  const float* __restrict__ enorm,
                                                  const float* __restrict__ tau_p,
                                                  float* __restrict__ out) {
    // [0, 8192) : two 4096-float staging buffers; later h_norm [64][132] (8448)
    __shared__ float smem[DE * LA];

    const int tid = threadIdx.x;
    const int lane = tid & 63;
    const int wv = tid >> 6;          // wave 0..3 -> tokens [wv*32, wv*32+32)
    const int lr = lane & 15;         // fragment row/col within 16
    const int lk = lane >> 4;         // k-group 0..3
    const long tok0 = (long)blockIdx.x * BM;

    f32x4 acc[2][4];                  // [row-tile][col-tile], 16x16 each
    #pragma unroll
    for (int rt = 0; rt < 2; ++rt)
        #pragma unroll
        for (int ct = 0; ct < 4; ++ct)
            acc[rt][ct] = (f32x4){0.f, 0.f, 0.f, 0.f};

    // per-lane staging source address pieces: flat=(wv*4+n)*64+lane, t=flat>>3, q=flat&7
    // issue: 4 x global_load_lds(16B) per wave per K-step
#define STAGE_ISSUE(CUR, KS)                                                   \
    {                                                                          \
        _Pragma("unroll")                                                      \
        for (int n = 0; n < 4; ++n) {                                          \
            const int flat = (wv * 4 + n) * 64 + lane;                         \
            const int t = flat >> 3, q = flat & 7;                             \
            const int qs = q ^ (t & 7);                                        \
            const float* g = h + (tok0 + t) * (long)KD + (KS) * 32 + qs * 4;   \
            float* l = smem + (CUR) * 4096 + (wv * 4 + n) * 256;               \
            __builtin_amdgcn_global_load_lds((gp1_t)(const void*)g,            \
                                             (lp3_t)(void*)l, 16, 0, 0);       \
        }                                                                      \
    }

    STAGE_ISSUE(0, 0);

    const int tt0 = wv * 32 + lr;       // token rows this lane reads
    const int tt1 = tt0 + 16;
    const int sw = lr & 7;              // XOR key (same for tt0, tt1)
    const int q0 = (lk * 2) ^ sw;       // LDS quad holding global quad lk*2
    const int q1 = (lk * 2 + 1) ^ sw;

    for (int ks = 0; ks < NS; ++ks) {
        const int cur = ks & 1;
        if (ks + 1 < NS) {
            STAGE_ISSUE(cur ^ 1, ks + 1);
            asm volatile("s_waitcnt vmcnt(4)" ::: "memory");  // cur resident; nxt in flight
        } else {
            asm volatile("s_waitcnt vmcnt(0)" ::: "memory");
        }
        __builtin_amdgcn_sched_barrier(0);
        __builtin_amdgcn_s_barrier();     // all waves' cur writes visible
        __builtin_amdgcn_sched_barrier(0);

        const float* base = smem + cur * 4096;
        float4 xl0 = *(const float4*)(base + tt0 * 32 + q0 * 4);
        float4 xh0 = *(const float4*)(base + tt0 * 32 + q1 * 4);
        float4 xl1 = *(const float4*)(base + tt1 * 32 + q0 * 4);
        float4 xh1 = *(const float4*)(base + tt1 * 32 + q1 * 4);

        s16x8 a1[2], a2[2], a3[2];
        split8(xl0, xh0, a1[0], a2[0], a3[0]);
        split8(xl1, xh1, a1[1], a2[1], a3[1]);

        const int k8 = ks * 4 + lk;
        #pragma unroll
        for (int ct = 0; ct < 4; ++ct) {
            const int bi = ((ct * 16 + lr) * 64 + k8) * 12;
            s16x8 b1 = ld_frag(wsW + bi);
            s16x8 b2 = ld_frag(wsW + bi + 4);
            s16x8 b3 = ld_frag(wsW + bi + 8);
            f32x4 c0 = acc[0][ct], c1 = acc[1][ct];
            c0 = __builtin_amdgcn_mfma_f32_16x16x32_bf16(a1[0], b1, c0, 0, 0, 0);
            c1 = __builtin_amdgcn_mfma_f32_16x16x32_bf16(a1[1], b1, c1, 0, 0, 0);
            c0 = __builtin_amdgcn_mfma_f32_16x16x32_bf16(a2[0], b1, c0, 0, 0, 0);
            c1 = __builtin_amdgcn_mfma_f32_16x16x32_bf16(a2[1], b1, c1, 0, 0, 0);
            c0 = __builtin_amdgcn_mfma_f32_16x16x32_bf16(a1[0], b2, c0, 0, 0, 0);
            c1 = __builtin_amdgcn_mfma_f32_16x16x32_bf16(a1[1], b2, c1, 0, 0, 0);
            c0 = __builtin_amdgcn_mfma_f32_16x16x32_bf16(a3[0], b1, c0, 0, 0, 0);
            c1 = __builtin_amdgcn_mfma_f32_16x16x32_bf16(a3[1], b1, c1, 0, 0, 0);
            c0 = __builtin_amdgcn_mfma_f32_16x16x32_bf16(a2[0], b2, c0, 0, 0, 0);
            c1 = __builtin_amdgcn_mfma_f32_16x16x32_bf16(a2[1], b2, c1, 0, 0, 0);
            c0 = __builtin_amdgcn_mfma_f32_16x16x32_bf16(a1[0], b3, c0, 0, 0, 0);
            c1 = __builtin_amdgcn_mfma_f32_16x16x32_bf16(a1[1], b3, c1, 0, 0, 0);
            acc[0][ct] = c0; acc[1][ct] = c1;
        }

        __builtin_amdgcn_s_barrier();     // all reads of cur done before overwrite
        __builtin_amdgcn_sched_barrier(0);
    }

    // ---- per-token L2 norm from fragments ----
    // C/D layout: col = lane&15 (d), row = (lane>>4)*4 + reg (token within 16)
    float inv_n[2][4];
    #pragma unroll
    for (int rt = 0; rt < 2; ++rt) {
        #pragma unroll
        for (int r = 0; r < 4; ++r) {
            float ss = 0.f;
            #pragma unroll
            for (int ct = 0; ct < 4; ++ct)
                ss = fmaf(acc[rt][ct][r], acc[rt][ct][r], ss);
            ss += __shfl_xor(ss, 1, 64);
            ss += __shfl_xor(ss, 2, 64);
            ss += __shfl_xor(ss, 4, 64);
            ss += __shfl_xor(ss, 8, 64);
            inv_n[rt][r] = 1.0f / fmaxf(sqrtf(ss), 1e-12f);
        }
    }

    // h_norm -> smem as [d][tok] (overlays staging buffers; last barrier protects)
    #pragma unroll
    for (int rt = 0; rt < 2; ++rt)
        #pragma unroll
        for (int ct = 0; ct < 4; ++ct)
            #pragma unroll
            for (int r = 0; r < 4; ++r) {
                const int d = ct * 16 + lr;
                const int t = wv * 32 + rt * 16 + lk * 4 + r;
                smem[d * LA + t] = acc[rt][ct][r] * inv_n[rt][r];
            }
    __syncthreads();   // full drain once; h_norm visible to all

    // ---- stage 2: scores[128][64] = h_norm @ e_norm^T (K=64), fp32 VALU ----
    const int tx = tid & 15;   // cols tx*4 + j
    const int ty = tid >> 4;   // tokens p*64 + ty*4 + i
    float sacc[2][4][4];
    #pragma unroll
    for (int p = 0; p < 2; ++p)
        #pragma unroll
        for (int i = 0; i < 4; ++i)
            #pragma unroll
            for (int j = 0; j < 4; ++j) sacc[p][i][j] = 0.0f;

    #pragma unroll 8
    for (int dd = 0; dd < DE; ++dd) {
        const float* ra = smem + dd * LA;
        float4 a0 = *(const float4*)(ra + ty * 4);
        float4 a1v = *(const float4*)(ra + 64 + ty * 4);
        float4 b  = *(const float4*)(enorm + dd * 64 + tx * 4);
        float av[2][4] = {{a0.x, a0.y, a0.z, a0.w}, {a1v.x, a1v.y, a1v.z, a1v.w}};
        float bv[4] = {b.x, b.y, b.z, b.w};
        #pragma unroll
        for (int p = 0; p < 2; ++p)
            #pragma unroll
            for (int i = 0; i < 4; ++i)
                #pragma unroll
                for (int j = 0; j < 4; ++j)
                    sacc[p][i][j] = fmaf(av[p][i], bv[j], sacc[p][i][j]);
    }

    // ---- epilogue: softmax, top-2, outputs ----
    const float inv_tau = 1.0f / tau_p[0];
    float* outS = out;                        // sparse_gates [NT][64]
    float* outI = out + (size_t)NT * 64;      // topk_indices [NT][2] (as float)
    float* outF = out + (size_t)NT * 66;      // full_gates   [NT][64]

    #pragma unroll
    for (int p = 0; p < 2; ++p) {
        #pragma unroll
        for (int i = 0; i < 4; ++i) {
            const long tok = tok0 + p * 64 + ty * 4 + i;
            float s[4];
            #pragma unroll
            for (int j = 0; j < 4; ++j) s[j] = sacc[p][i][j] * inv_tau;

            float m = fmaxf(fmaxf(s[0], s[1]), fmaxf(s[2], s[3]));
            m = fmaxf(m, __shfl_xor(m, 1, 64));
            m = fmaxf(m, __shfl_xor(m, 2, 64));
            m = fmaxf(m, __shfl_xor(m, 4, 64));
            m = fmaxf(m, __shfl_xor(m, 8, 64));

            float g[4], z = 0.f;
            #pragma unroll
            for (int j = 0; j < 4; ++j) { g[j] = __expf(s[j] - m); z += g[j]; }
            z += __shfl_xor(z, 1, 64);
            z += __shfl_xor(z, 2, 64);
            z += __shfl_xor(z, 4, 64);
            z += __shfl_xor(z, 8, 64);
            const float invZ = 1.0f / z;

            *(float4*)(outF + tok * 64 + tx * 4) =
                make_float4(g[0] * invZ, g[1] * invZ, g[2] * invZ, g[3] * invZ);

            // top-2 on s (monotone with gates); ties -> lower index (jax top_k)
            float v1 = -3.4e38f, v2 = -3.4e38f;
            int i1 = 1 << 20, i2 = 1 << 20;
            #pragma unroll
            for (int j = 0; j < 4; ++j) {
                float v = s[j];
                int e = tx * 4 + j;
                if (v > v1 || (v == v1 && e < i1)) { v2 = v1; i2 = i1; v1 = v; i1 = e; }
                else if (v > v2 || (v == v2 && e < i2)) { v2 = v; i2 = e; }
            }
            #pragma unroll
            for (int msk = 1; msk <= 8; msk <<= 1) {
                float o1 = __shfl_xor(v1, msk, 64); int oi1 = __shfl_xor(i1, msk, 64);
                float o2 = __shfl_xor(v2, msk, 64); int oi2 = __shfl_xor(i2, msk, 64);
                if (o1 > v1 || (o1 == v1 && oi1 < i1)) {
                    if (v1 > o2 || (v1 == o2 && i1 < oi2)) { v2 = v1; i2 = i1; }
                    else { v2 = o2; i2 = oi2; }
                    v1 = o1; i1 = oi1;
                } else {
                    if (o1 > v2 || (o1 == v2 && oi1 < i2)) { v2 = o1; i2 = oi1; }
                }
            }

            // softmax over the two top GATE values
            float gv1 = __expf(v1 - m) * invZ;
            float gv2 = __expf(v2 - m) * invZ;
            float qq = __expf(gv2 - gv1);
            float w1 = 1.0f / (1.0f + qq);
            float w2 = qq * w1;

            float sp[4];
            #pragma unroll
            for (int j = 0; j < 4; ++j) {
                int e = tx * 4 + j;
                sp[j] = (e == i1) ? w1 : ((e == i2) ? w2 : 0.0f);
            }
            *(float4*)(outS + tok * 64 + tx * 4) = make_float4(sp[0], sp[1], sp[2], sp[3]);
            if (tx == 0) {
                *(float2*)(outI + tok * 2) = make_float2((float)i1, (float)i2);
            }
        }
    }
#undef STAGE_ISSUE
}

extern "C" void kernel_launch(void* const* d_in, const int* in_sizes, int n_in,
                              void* d_out, int out_size, void* d_ws, size_t ws_size,
                              hipStream_t stream) {
    const float* h   = (const float*)d_in[0];
    const float* W   = (const float*)d_in[1];
    const float* E   = (const float*)d_in[2];
    const float* tau = (const float*)d_in[3];
    float* out = (float*)d_out;
    unsigned int* ws = (unsigned int*)d_ws;   // 192KB W frags + 16KB e_norm^T

    prep<<<17, 256, 0, stream>>>(W, E, ws);
    moe_all<<<NT / BM, 256, 0, stream>>>(h, ws, (const float*)(ws + WS_EN), tau, out);
}